// Round 5
// baseline (86.484 us; speedup 1.0000x reference)
//
#include <hip/hip_runtime.h>

// QuanvolutionClassifier — fully fused single kernel.
// R3: U = U01 (x) U23 factorization (CX(0,1), CX(2,3) never couple pairs).
// R4: build_U fused in-kernel; 32 U coeffs pinned to SGPRs via readfirstlane.
// R5: phase-1 processes a PAIR of adjacent patches per task (2x dwordx4 loads
//     per 2 patches, addressing amortized), and sincos folded to one v_mul
//     (1/4pi, revolutions) + raw v_sin/v_cos per pixel.

#define RPB 4           // rows (batch images) per block
#define NPIX 784
#define NPATCH 196
#define NPAIR 98        // horizontal patch pairs per image
#define INV4PI 0.07957747154594767f   // 0.5 rad * (1/2pi) per unit pixel

__device__ __forceinline__ float rfl(float v) {
    return __uint_as_float(__builtin_amdgcn_readfirstlane(__float_as_uint(v)));
}

// One patch: wires (t0,t1,b0,b1) = pixels [r,c],[r,c+1],[r+1,c],[r+1,c+1].
// ca/sa etc are cos/sin of pixel/2. Returns (e0,e1,e2,e3).
__device__ __forceinline__ float4 patch_feat(const float* Ua, const float* Ub,
                                             float c0, float s0, float c1, float s1,
                                             float c2, float s2, float c3, float s3) {
    float pa0 = c0 * c1, pa1 = c0 * s1, pa2 = s0 * c1, pa3 = s0 * s1;
    float pb0 = c2 * c3, pb1 = c2 * s3, pb2 = s2 * c3, pb3 = s2 * s3;
    float qa[4], qb[4];
#pragma unroll
    for (int s = 0; s < 4; ++s) {
        float ya = fmaf(Ua[s * 4 + 3], pa3,
                   fmaf(Ua[s * 4 + 2], pa2,
                   fmaf(Ua[s * 4 + 1], pa1, Ua[s * 4 + 0] * pa0)));
        float yb = fmaf(Ub[s * 4 + 3], pb3,
                   fmaf(Ub[s * 4 + 2], pb2,
                   fmaf(Ub[s * 4 + 1], pb1, Ub[s * 4 + 0] * pb0)));
        qa[s] = ya * ya;
        qb[s] = yb * yb;
    }
    return make_float4((qa[0] + qa[1]) - (qa[2] + qa[3]),
                       (qa[0] - qa[1]) + (qa[2] - qa[3]),
                       (qb[0] + qb[1]) - (qb[2] + qb[3]),
                       (qb[0] - qb[1]) + (qb[2] - qb[3]));
}

__launch_bounds__(256, 8)   // 8 waves/EU -> VGPR<=64, 8 blocks/CU, 32 waves/CU
__global__ void quanv_kernel(const float* __restrict__ x,
                             const float* __restrict__ params,
                             const float* __restrict__ W,
                             const float* __restrict__ bias,
                             float* __restrict__ out,
                             int n_rows) {
    __shared__ __align__(16) float feat[RPB * NPIX];   // 12544 B
    __shared__ float Ush[32];                          // U01 | U23
    const int tid = threadIdx.x;
    const int row0 = blockIdx.x * RPB;

    // ---- build U01/U23 (8 lanes, ~100 FLOPs, redundant per block) ----
    if (tid < 8) {
        int pair = tid >> 2;      // 0 -> wires {0,1}, 1 -> wires {2,3}
        int col  = tid & 3;       // basis column
        float st[4];
#pragma unroll
        for (int i = 0; i < 4; ++i) st[i] = (i == col) ? 1.0f : 0.0f;
#pragma unroll
        for (int l = 0; l < 4; ++l) {
            float ah = 0.5f * params[l * 4 + pair * 2 + 0];
            float al = 0.5f * params[l * 4 + pair * 2 + 1];
            float ch = cosf(ah), sh = sinf(ah);
#pragma unroll
            for (int j = 0; j < 2; ++j) {                     // RY on high bit
                float u = st[j], w = st[j + 2];
                st[j]     = ch * u - sh * w;
                st[j + 2] = sh * u + ch * w;
            }
            float cl = cosf(al), sl = sinf(al);
#pragma unroll
            for (int j = 0; j < 4; j += 2) {                  // RY on low bit
                float u = st[j], w = st[j + 1];
                st[j]     = cl * u - sl * w;
                st[j + 1] = sl * u + cl * w;
            }
            float tmp = st[2]; st[2] = st[3]; st[3] = tmp;    // CX: swap |10>,|11>
        }
#pragma unroll
        for (int s = 0; s < 4; ++s) Ush[pair * 16 + s * 4 + col] = st[s];
    }
    __syncthreads();

    // pin the 32 wave-uniform coeffs into SGPRs
    float Ua[16], Ub[16];
#pragma unroll
    for (int i = 0; i < 16; ++i) { Ua[i] = rfl(Ush[i]); Ub[i] = rfl(Ush[16 + i]); }

    // ---------------- phase 1: per-patch-pair quantum features ----------------
    for (int g = tid; g < RPB * NPAIR; g += 256) {
        int r  = g / NPAIR;                  // local row in block
        int j  = g - r * NPAIR;              // pair id 0..97
        int Pr = j / 7;                      // patch row 0..13
        int c  = j - Pr * 7;                 // pair col 0..6 (patches 2c, 2c+1)
        int grow = row0 + r;
        if (grow < n_rows) {
            const float* px = x + (size_t)grow * NPIX + Pr * 56 + c * 4;
            float4 top = *(const float4*)px;          // row 2Pr,  cols 4c..4c+3
            float4 bot = *(const float4*)(px + 28);   // row 2Pr+1, cols 4c..4c+3

            float u, sA0, cA0, sA1, cA1, sA2, cA2, sA3, cA3;
            float sB0, cB0, sB1, cB1, sB2, cB2, sB3, cB3;
            u = top.x * INV4PI; sA0 = __builtin_amdgcn_sinf(u); cA0 = __builtin_amdgcn_cosf(u);
            u = top.y * INV4PI; sA1 = __builtin_amdgcn_sinf(u); cA1 = __builtin_amdgcn_cosf(u);
            u = bot.x * INV4PI; sA2 = __builtin_amdgcn_sinf(u); cA2 = __builtin_amdgcn_cosf(u);
            u = bot.y * INV4PI; sA3 = __builtin_amdgcn_sinf(u); cA3 = __builtin_amdgcn_cosf(u);
            u = top.z * INV4PI; sB0 = __builtin_amdgcn_sinf(u); cB0 = __builtin_amdgcn_cosf(u);
            u = top.w * INV4PI; sB1 = __builtin_amdgcn_sinf(u); cB1 = __builtin_amdgcn_cosf(u);
            u = bot.z * INV4PI; sB2 = __builtin_amdgcn_sinf(u); cB2 = __builtin_amdgcn_cosf(u);
            u = bot.w * INV4PI; sB3 = __builtin_amdgcn_sinf(u); cB3 = __builtin_amdgcn_cosf(u);

            int P0 = Pr * 14 + 2 * c;
            float4 eA = patch_feat(Ua, Ub, cA0, sA0, cA1, sA1, cA2, sA2, cA3, sA3);
            float4 eB = patch_feat(Ua, Ub, cB0, sB0, cB1, sB1, cB2, sB2, cB3, sB3);
            *(float4*)&feat[r * NPIX + 4 * P0]     = eA;
            *(float4*)&feat[r * NPIX + 4 * P0 + 4] = eB;
        }
    }
    __syncthreads();

    // ---------------- phase 2: feat @ W^T + b, log_softmax ----------------
    const int wid = tid >> 6, lane = tid & 63;
    const float4* W4 = (const float4*)W;               // W4[o*196 + k]
    for (int r = wid; r < RPB; r += 4) {
        int grow = row0 + r;
        if (grow >= n_rows) break;
        float acc[10];
#pragma unroll
        for (int o = 0; o < 10; ++o) acc[o] = 0.f;
        const float4* frow4 = (const float4*)&feat[r * NPIX];   // 196 float4
        for (int k = lane; k < NPATCH; k += 64) {
            float4 f = frow4[k];
#pragma unroll
            for (int o = 0; o < 10; ++o) {
                float4 w = W4[o * NPATCH + k];
                acc[o] = fmaf(f.x, w.x, fmaf(f.y, w.y, fmaf(f.z, w.z, fmaf(f.w, w.w, acc[o]))));
            }
        }
#pragma unroll
        for (int o = 0; o < 10; ++o) {
            acc[o] += __shfl_xor(acc[o], 32, 64);
            acc[o] += __shfl_xor(acc[o], 16, 64);
            acc[o] += __shfl_xor(acc[o], 8, 64);
            acc[o] += __shfl_xor(acc[o], 4, 64);
            acc[o] += __shfl_xor(acc[o], 2, 64);
            acc[o] += __shfl_xor(acc[o], 1, 64);
        }
        if (lane == 0) {
            float lg[10], mx = -1e30f;
#pragma unroll
            for (int o = 0; o < 10; ++o) { lg[o] = acc[o] + bias[o]; mx = fmaxf(mx, lg[o]); }
            float sum = 0.f;
#pragma unroll
            for (int o = 0; o < 10; ++o) sum += __expf(lg[o] - mx);
            float lse = mx + __logf(sum);
#pragma unroll
            for (int o = 0; o < 10; ++o) out[(size_t)grow * 10 + o] = lg[o] - lse;
        }
    }
}

extern "C" void kernel_launch(void* const* d_in, const int* in_sizes, int n_in,
                              void* d_out, int out_size, void* d_ws, size_t ws_size,
                              hipStream_t stream) {
    const float* x      = (const float*)d_in[0];
    const float* params = (const float*)d_in[1];
    const float* W      = (const float*)d_in[2];
    const float* b      = (const float*)d_in[3];
    float* out = (float*)d_out;

    int n_rows = in_sizes[0] / NPIX;   // 8192
    int nblocks = (n_rows + RPB - 1) / RPB;
    hipLaunchKernelGGL(quanv_kernel, dim3(nblocks), dim3(256), 0, stream,
                       x, params, W, b, out, n_rows);
}